// Round 6
// baseline (1512.238 us; speedup 1.0000x reference)
//
#include <hip/hip_runtime.h>
#include <cfloat>
#include <math.h>

#define NPTS   5000
#define BATCH  2
#define DIM    128
#define NBINS  10
#define BINSZ  500
#define TOPK   5
#define NCAND  8      // fp32 screening width (top-8 covers fp64 top-5 w/ huge margin)
#define ROTCOLS 100   // rotations stored [128, 100]; we use first NBINS/2 = 5

// ---------------- Kernel A: bin assignment + squared norms (fp64 acc) -----
#define KB_PTS 64
#define KB_STR 129
__global__ void k_bins(const float* __restrict__ pts, const float* __restrict__ rot,
                       int* __restrict__ bin_idx, double* __restrict__ na) {
    __shared__ float P[KB_PTS * KB_STR];
    __shared__ float rotL[DIM * 5];
    int tid = threadIdx.x;
    for (int f = tid; f < DIM * 5; f += 256)
        rotL[f] = rot[(f / 5) * ROTCOLS + (f % 5)];

    int p0  = blockIdx.x * KB_PTS;
    int npb = min(KB_PTS, BATCH * NPTS - p0);

    for (int f = tid; f < npb * DIM; f += 256) {
        int r = f >> 7, d = f & 127;
        P[r * KB_STR + d] = pts[(size_t)(p0 + r) * DIM + d];
    }
    __syncthreads();

    int p = tid >> 2;    // point within block
    int s = tid & 3;     // dim quarter
    double acc[5] = {0., 0., 0., 0., 0.};
    double sq = 0.;
    const float* row = &P[p * KB_STR + s * 32];
    for (int j = 0; j < 32; ++j) {
        double v = (double)row[j];
        sq += v * v;
        int d = s * 32 + j;
#pragma unroll
        for (int h = 0; h < 5; ++h) acc[h] += v * (double)rotL[d * 5 + h];
    }
#pragma unroll
    for (int m = 1; m < 4; m <<= 1) {
#pragma unroll
        for (int h = 0; h < 5; ++h) acc[h] += __shfl_xor(acc[h], m, 4);
        sq += __shfl_xor(sq, m, 4);
    }
    if (s == 0 && p < npb) {
        double best = acc[0]; int bc = 0;
#pragma unroll
        for (int c = 1; c < NBINS; ++c) {
            double v = (c < 5) ? acc[c] : -acc[c - 5];
            if (v > best) { best = v; bc = c; }
        }
        bin_idx[p0 + p] = bc;
        na[p0 + p] = sq;
    }
}

// ---------------- Kernel B: stable counting sort (== stable argsort) ------
__global__ void k_sort(const int* __restrict__ bin_idx, int* __restrict__ order) {
    const int b = blockIdx.x;
    const int t = threadIdx.x;               // 256 threads
    const int NPT = (NPTS + 255) / 256;      // 20
    int start = t * NPT;
    int end   = min(NPTS, start + NPT);

    int cnt[NBINS];
#pragma unroll
    for (int c = 0; c < NBINS; ++c) cnt[c] = 0;
    for (int i = start; i < end; ++i) {
        int c = bin_idx[b * NPTS + i];
#pragma unroll
        for (int k = 0; k < NBINS; ++k) cnt[k] += (c == k);
    }

    __shared__ int hist[NBINS * 256];
#pragma unroll
    for (int c = 0; c < NBINS; ++c) hist[c * 256 + t] = cnt[c];
    __syncthreads();

    int base = t * NBINS;
    int s = 0;
#pragma unroll
    for (int k = 0; k < NBINS; ++k) s += hist[base + k];
    __shared__ int scan[256];
    scan[t] = s;
    __syncthreads();
    for (int off = 1; off < 256; off <<= 1) {
        int v = (t >= off) ? scan[t - off] : 0;
        __syncthreads();
        scan[t] += v;
        __syncthreads();
    }
    int run = scan[t] - s;
#pragma unroll
    for (int k = 0; k < NBINS; ++k) { int h = hist[base + k]; hist[base + k] = run; run += h; }
    __syncthreads();

    int ofs[NBINS];
#pragma unroll
    for (int c = 0; c < NBINS; ++c) ofs[c] = hist[c * 256 + t];
    for (int i = start; i < end; ++i) {
        int c = bin_idx[b * NPTS + i];
        int pos = 0;
#pragma unroll
        for (int k = 0; k < NBINS; ++k) {
            if (c == k) pos = ofs[k];
            ofs[k] += (c == k);
        }
        order[b * NPTS + pos] = i;
    }
}

// ------- Kernel C: fp32 gram screen -> top-8 per row + zero-fill ----------
#define RT    16
#define NRT   32
#define CTILE 64
#define RSTR  132
#define NCT   8
#define ROWQ  (NPTS/4)

__launch_bounds__(256, 3)
__global__ void k_screen(const float* __restrict__ pts, const double* __restrict__ na,
                         const int* __restrict__ order, int* __restrict__ cand8,
                         float* __restrict__ out) {
    __shared__ float rowP[RT * RSTR];
    __shared__ float colP[CTILE * RSTR];
    __shared__ float naC[CTILE];
    __shared__ float naRs[RT];
    __shared__ int   ordR[RT];

    int blk   = blockIdx.x;
    int rt    = blk & (NRT - 1);
    int chunk = blk >> 5;          // 0..19
    int b     = chunk / NBINS;
    int c     = chunk % NBINS;
    int tid   = threadIdx.x;
    int row0  = rt * RT;
    int rowCount = min(RT, BINSZ - row0);   // 16, except last tile: 4

    const int*   ordBase = order + b * NPTS + c * BINSZ;
    const float* ptsB    = pts + (size_t)b * NPTS * DIM;

    for (int f = tid; f < rowCount * (DIM / 4); f += 256) {
        int r = f / (DIM / 4);
        int q = f % (DIM / 4);
        int g = ordBase[row0 + r];
        float4 v = *(const float4*)(ptsB + (size_t)g * DIM + q * 4);
        *(float4*)(&rowP[r * RSTR + q * 4]) = v;
    }
    if (tid < rowCount) {
        int g = ordBase[row0 + tid];
        ordR[tid] = g;
        naRs[tid] = (float)na[b * NPTS + g];
    }
    __syncthreads();

    int rg = tid >> 4;   // 0..15: this thread's row
    int cg = tid & 15;   // cols cg + 16*jj

    float naRr = (rg < rowCount) ? naRs[rg] : 0.f;

    // packed key: (fp32 d2 bits << 32) | local idx. d2 > 0 always, so u64
    // ascending order == (d2 asc, idx asc) exactly.
    unsigned long long tv[NCAND];
#pragma unroll
    for (int k = 0; k < NCAND; ++k) tv[k] = 0xFFFFFFFFFFFFFFFFull;

    const int totalZ = rowCount * ROWQ;

    for (int ct = 0; ct < NCT; ++ct) {
        int col0 = ct * CTILE;
        int colCount = min(CTILE, BINSZ - col0);
        __syncthreads();
        for (int f = tid; f < colCount * (DIM / 4); f += 256) {
            int j = f / (DIM / 4);
            int q = f % (DIM / 4);
            int g = ordBase[col0 + j];
            float4 v = *(const float4*)(ptsB + (size_t)g * DIM + q * 4);
            *(float4*)(&colP[j * RSTR + q * 4]) = v;
        }
        if (tid < colCount) {
            int g = ordBase[col0 + tid];
            naC[tid] = (float)na[b * NPTS + g];
        }
        __syncthreads();

        // zero-fill slice ct: drains during this tile's compute
        {
            float4 z = make_float4(0.f, 0.f, 0.f, 0.f);
            int z0 = (ct * totalZ) / NCT, z1 = ((ct + 1) * totalZ) / NCT;
            for (int f = z0 + tid; f < z1; f += 256) {
                int r = f / ROWQ;
                int q = f - r * ROWQ;
                float* outRow = out + ((size_t)b * NPTS + ordR[r]) * NPTS;
                *(float4*)(outRow + 4 * q) = z;
            }
        }

        float acc[4];
#pragma unroll
        for (int jj = 0; jj < 4; ++jj) acc[jj] = 0.f;

        const float4* rowP4 = (const float4*)(rowP);
        const float4* colP4 = (const float4*)(colP);
        for (int q = 0; q < DIM / 4; ++q) {
            float4 a = rowP4[rg * (RSTR / 4) + q];
            float4 bb[4];
#pragma unroll
            for (int jj = 0; jj < 4; ++jj) bb[jj] = colP4[(cg + 16 * jj) * (RSTR / 4) + q];
#pragma unroll
            for (int jj = 0; jj < 4; ++jj) {
                acc[jj] += a.x * bb[jj].x + a.y * bb[jj].y
                         + a.z * bb[jj].z + a.w * bb[jj].w;
            }
        }

#pragma unroll
        for (int jj = 0; jj < 4; ++jj) {
            int j = cg + 16 * jj;
            if (j < colCount) {
                float key = fmaxf(naRr + naC[j] - 2.f * acc[jj], 1e-6f);
                unsigned long long pk =
                    ((unsigned long long)__float_as_uint(key) << 32)
                    | (unsigned int)(col0 + j);
                if (pk < tv[NCAND - 1]) {
#pragma unroll
                    for (int k = 0; k < NCAND; ++k) {
                        bool lt = pk < tv[k];
                        unsigned long long ov = tv[k];
                        if (lt) { tv[k] = pk; pk = ov; }
                    }
                }
            }
        }
    }

    // merge the 16 column-threads' sorted top-8 lists (butterfly, width 16)
#pragma unroll
    for (int m = 1; m < 16; m <<= 1) {
        unsigned long long rv[NCAND];
#pragma unroll
        for (int k = 0; k < NCAND; ++k) rv[k] = __shfl_xor(tv[k], m, 16);
#pragma unroll
        for (int k = 0; k < NCAND; ++k) {
            unsigned long long cv = rv[k];
#pragma unroll
            for (int s = 0; s < NCAND; ++s) {
                bool lt = cv < tv[s];
                unsigned long long ov = tv[s];
                if (lt) { tv[s] = cv; cv = ov; }
            }
        }
    }

    // write the 8 surviving local indices for this row
    if (cg == 0 && rg < rowCount) {
        int rowIdx = b * NPTS + c * BINSZ + row0 + rg;   // sorted-row index
#pragma unroll
        for (int k = 0; k < NCAND; ++k)
            cand8[rowIdx * NCAND + k] = (int)(unsigned int)tv[k];
    }
}

// ------- Kernel D: fp64 refine of 8 candidates/row + scatter --------------
#define RF_ROWS 4
__global__ void k_refine(const float* __restrict__ pts, const double* __restrict__ na,
                         const int* __restrict__ order, const int* __restrict__ cand8,
                         float* __restrict__ out) {
    __shared__ double keyL[RF_ROWS * NCAND];
    __shared__ int    dstL[RF_ROWS * NCAND];
    __shared__ int    lidL[RF_ROWS * NCAND];

    int tid  = threadIdx.x;
    int rsub = tid >> 6;                       // 0..3: row within block
    int row  = blockIdx.x * RF_ROWS + rsub;    // 0..9999 (sorted-row index)
    int lane = tid & 63;
    int cand = lane >> 3;                      // 0..7
    int dg   = lane & 7;                       // 0..7: 16-dim group

    int b   = row / NPTS;
    int pos = row - b * NPTS;
    int src = order[row];
    int binb = row - (pos % BINSZ);            // base of this row's bin in `order`
    int lid  = cand8[row * NCAND + cand];
    int dst  = order[binb + lid];

    const float4* ps4 = (const float4*)(pts + ((size_t)b * NPTS + src) * DIM);
    const float4* pd4 = (const float4*)(pts + ((size_t)b * NPTS + dst) * DIM);
    double g = 0.;
#pragma unroll
    for (int q = 0; q < 4; ++q) {
        float4 x = ps4[dg * 4 + q];
        float4 y = pd4[dg * 4 + q];
        g += (double)x.x * (double)y.x + (double)x.y * (double)y.y
           + (double)x.z * (double)y.z + (double)x.w * (double)y.w;
    }
#pragma unroll
    for (int m = 1; m < 8; m <<= 1) g += __shfl_xor(g, m, 8);

    if (dg == 0) {
        double key = fmax(na[b * NPTS + src] + na[b * NPTS + dst] - 2. * g, 1e-6);
        keyL[rsub * NCAND + cand] = key;
        dstL[rsub * NCAND + cand] = dst;
        lidL[rsub * NCAND + cand] = lid;
    }
    __syncthreads();

    if (lane == 0) {
        float* outRow = out + ((size_t)b * NPTS + src) * NPTS;
        bool used[NCAND];
#pragma unroll
        for (int k = 0; k < NCAND; ++k) used[k] = false;
#pragma unroll
        for (int k = 0; k < TOPK; ++k) {       // select k-th smallest (key, lid)
            int best = -1;
            double bk = DBL_MAX; int bl = 0x7fffffff;
            for (int m = 0; m < NCAND; ++m) {
                if (!used[m]) {
                    double kv = keyL[rsub * NCAND + m];
                    int    lv = lidL[rsub * NCAND + m];
                    if (kv < bk || (kv == bk && lv < bl)) { bk = kv; bl = lv; best = m; }
                }
            }
            used[best] = true;
            outRow[dstL[rsub * NCAND + best]] = (float)exp(-0.1 * sqrt(bk));
        }
    }
}

// ---------------- launch ----------------
extern "C" void kernel_launch(void* const* d_in, const int* in_sizes, int n_in,
                              void* d_out, int out_size, void* d_ws, size_t ws_size,
                              hipStream_t stream) {
    const float* pts = (const float*)d_in[0];   // [2,5000,128]
    const float* rot = (const float*)d_in[1];   // [128,100]
    float* out = (float*)d_out;                 // [2,5000,5000]

    double* na      = (double*)d_ws;                                    // 80000 B
    int*    bin_idx = (int*)((char*)d_ws + 80000);                      // 40000 B
    int*    order   = (int*)((char*)d_ws + 120000);                     // 40000 B
    int*    cand8   = (int*)((char*)d_ws + 160000);                     // 320000 B

    k_bins<<<(BATCH * NPTS + KB_PTS - 1) / KB_PTS, 256, 0, stream>>>(pts, rot, bin_idx, na);
    k_sort<<<BATCH, 256, 0, stream>>>(bin_idx, order);
    k_screen<<<BATCH * NBINS * NRT, 256, 0, stream>>>(pts, na, order, cand8, out);
    k_refine<<<(BATCH * NPTS) / RF_ROWS, 256, 0, stream>>>(pts, na, order, cand8, out);
}